// Round 1
// baseline (2366.002 us; speedup 1.0000x reference)
//
#include <hip/hip_runtime.h>
#include <hip/hip_bf16.h>
#include <math.h>

// Problem constants
#define BB 4
#define NN 2048
#define DD 64
#define NM (NN*NN)            // 4194304 per batch
#define ITERS 8               // mathematically == 50 iters (contraction fi^2 ~ 1e-4/iter)
#define FI 0.009900990099009901f   // tau/(tau+eps) = 0.001/0.101
#define MU (1.0f/2048.0f)          // mu == nu == 1/N
#define EPS_DEN 1e-30f

typedef unsigned short u16;

static __device__ __forceinline__ float bf2f(u16 x){
    unsigned int u = ((unsigned int)x) << 16;
    return __uint_as_float(u);
}
static __device__ __forceinline__ u16 f2bf(float f){
    unsigned int u = __float_as_uint(f);
    unsigned int r = (u + 0x7FFFu + ((u >> 16) & 1u)) >> 16;  // round-to-nearest-even
    return (u16)r;
}

// ---------------- normalize: xn = x / (||x||_2 + 1e-8), row-wise over D=64 ----------------
__global__ void norm_k(const float* __restrict__ x, float* __restrict__ xn){
    int row  = blockIdx.x * 4 + (threadIdx.x >> 6);   // 4 waves/block, 1 row/wave
    int lane = threadIdx.x & 63;
    float v = x[row * DD + lane];
    float ss = v * v;
    #pragma unroll
    for (int o = 32; o >= 1; o >>= 1) ss += __shfl_xor(ss, o, 64);
    float s = 1.0f / (sqrtf(ss) + 1e-8f);
    xn[row * DD + lane] = v * s;
}

// ---------------- Gibbs kernel: K[b,n,m] = exp(10*dot(A[b,n],B[b,m]) - 10), bf16 out -------
__global__ void gibbs_k(const float* __restrict__ A, const float* __restrict__ Bm,
                        u16* __restrict__ K){
    __shared__ float As[64][65];
    __shared__ float Bs[64][65];
    int b  = blockIdx.z;
    int n0 = blockIdx.y * 64, m0 = blockIdx.x * 64;
    int tx = threadIdx.x, ty = threadIdx.y;
    int tid = ty * 16 + tx;
    const float* Ab = A + ((size_t)b * NN + n0) * DD;
    const float* Bb = Bm + ((size_t)b * NN + m0) * DD;
    #pragma unroll
    for (int i = 0; i < 16; i++){
        int lin = tid + 256 * i;          // 4096 elements
        int r = lin >> 6, c = lin & 63;
        As[r][c] = Ab[r * DD + c];
        Bs[r][c] = Bb[r * DD + c];
    }
    __syncthreads();
    float acc[4][4] = {};
    #pragma unroll
    for (int k = 0; k < 64; k++){
        float a[4], bv[4];
        #pragma unroll
        for (int i = 0; i < 4; i++) a[i]  = As[ty * 4 + i][k];
        #pragma unroll
        for (int j = 0; j < 4; j++) bv[j] = Bs[tx * 4 + j][k];
        #pragma unroll
        for (int i = 0; i < 4; i++)
            #pragma unroll
            for (int j = 0; j < 4; j++)
                acc[i][j] = fmaf(a[i], bv[j], acc[i][j]);
    }
    u16* Kb = K + (size_t)b * NM;
    #pragma unroll
    for (int i = 0; i < 4; i++){
        int n = n0 + ty * 4 + i;
        #pragma unroll
        for (int j = 0; j < 4; j++){
            int m = m0 + tx * 4 + j;
            float kv = expf(fmaf(10.0f, acc[i][j], -10.0f));
            Kb[(size_t)n * NN + m] = f2bf(kv);
        }
    }
}

// ---------------- init: u=1 for all three uots, zero t buffers + accumulator ----------------
__global__ void init_k(float* u1, float* u2, float* u3, float* t0, float* t1, float* accum){
    int i = blockIdx.x * 256 + threadIdx.x;   // 8192
    u1[i] = 1.0f; u2[i] = 1.0f; u3[i] = 1.0f;
    t0[i] = 0.0f; t1[i] = 0.0f;
    if (i == 0) accum[0] = 0.0f;
}

// ---------------- t = K^T u (column sums weighted by u), atomic partials -------------------
__global__ void colsum_k(const u16* __restrict__ K, const float* __restrict__ u,
                         float* __restrict__ t){
    // grid (B, N/256, 32), block 256
    int b = blockIdx.x;
    int m = blockIdx.y * 256 + threadIdx.x;
    int n0 = blockIdx.z * 64;
    const u16* Kp = K + ((size_t)b * NN + n0) * NN + m;
    const float* up = u + b * NN + n0;
    float acc = 0.0f;
    #pragma unroll 8
    for (int n = 0; n < 64; n++) acc += bf2f(Kp[(size_t)n * NN]) * up[n];
    atomicAdd(&t[b * NN + m], acc);
}

// ---- v = (nu/(t+eps))^fi (in LDS, +global store); u = (mu/(K v+eps))^fi; zero next t ------
__global__ void rowsum_k(const u16* __restrict__ K, const float* __restrict__ t,
                         float* __restrict__ u, float* __restrict__ v,
                         float* __restrict__ tnext){
    // grid (B, N/4), block 256: wave per row
    __shared__ float vsh[NN];
    int b = blockIdx.x, rg = blockIdx.y;
    int tid = threadIdx.x;
    for (int m = tid; m < NN; m += 256)
        vsh[m] = powf(MU / (t[b * NN + m] + EPS_DEN), FI);
    __syncthreads();
    if (rg == 0){
        for (int m = tid; m < NN; m += 256){
            v[b * NN + m] = vsh[m];
            tnext[b * NN + m] = 0.0f;
        }
    }
    int wave = tid >> 6, lane = tid & 63;
    int n = rg * 4 + wave;
    const u16* Kp = K + ((size_t)b * NN + n) * NN;
    float acc = 0.0f;
    for (int m = lane; m < NN; m += 64) acc += bf2f(Kp[m]) * vsh[m];
    #pragma unroll
    for (int o = 32; o >= 1; o >>= 1) acc += __shfl_xor(acc, o, 64);
    if (lane == 0) u[b * NN + n] = powf(MU / (acc + EPS_DEN), FI);
}

// ---------------- w = v1 * u2 --------------------------------------------------------------
__global__ void w_k(const float* __restrict__ v1, const float* __restrict__ u2,
                    float* __restrict__ w){
    int i = blockIdx.x * 256 + threadIdx.x;
    w[i] = v1[i] * u2[i];
}

// ---- fused final: C = K1*diag(w)*K2; loss-partial = sum |u3 K3 v3 - u1 C v2|; atomic ------
__global__ void fgemm_k(const u16* __restrict__ K1, const u16* __restrict__ K2,
                        const u16* __restrict__ K3, const float* __restrict__ w,
                        const float* __restrict__ u1, const float* __restrict__ v2,
                        const float* __restrict__ u3, const float* __restrict__ v3,
                        float* __restrict__ accum){
    __shared__ float As[64][17];
    __shared__ float Bs[16][65];
    __shared__ float red[4];
    int b = blockIdx.z;
    int n0 = blockIdx.y * 64, m0 = blockIdx.x * 64;
    int tx = threadIdx.x, ty = threadIdx.y;
    int tid = ty * 16 + tx;
    const u16* K1b = K1 + (size_t)b * NM;
    const u16* K2b = K2 + (size_t)b * NM;
    float acc[4][4] = {};
    for (int k0 = 0; k0 < NN; k0 += 16){
        __syncthreads();
        #pragma unroll
        for (int i = 0; i < 4; i++){
            int lin = tid + 256 * i;                // 1024 elems each array
            int r = lin >> 4, c = lin & 15;         // As: 64 x 16
            As[r][c] = bf2f(K1b[(size_t)(n0 + r) * NN + k0 + c]) * w[b * NN + k0 + c];
            int r2 = lin >> 6, c2 = lin & 63;       // Bs: 16 x 64
            Bs[r2][c2] = bf2f(K2b[(size_t)(k0 + r2) * NN + m0 + c2]);
        }
        __syncthreads();
        #pragma unroll
        for (int kk = 0; kk < 16; kk++){
            float a[4], bv[4];
            #pragma unroll
            for (int i = 0; i < 4; i++) a[i]  = As[ty * 4 + i][kk];
            #pragma unroll
            for (int j = 0; j < 4; j++) bv[j] = Bs[kk][tx * 4 + j];
            #pragma unroll
            for (int i = 0; i < 4; i++)
                #pragma unroll
                for (int j = 0; j < 4; j++)
                    acc[i][j] = fmaf(a[i], bv[j], acc[i][j]);
        }
    }
    // epilogue: |f_dir - f_ind| partial sum
    const u16* K3b = K3 + (size_t)b * NM;
    float part = 0.0f;
    #pragma unroll
    for (int i = 0; i < 4; i++){
        int n = n0 + ty * 4 + i;
        float u1n = u1[b * NN + n], u3n = u3[b * NN + n];
        #pragma unroll
        for (int j = 0; j < 4; j++){
            int m = m0 + tx * 4 + j;
            float find = u1n * acc[i][j] * v2[b * NN + m];
            float fdir = u3n * bf2f(K3b[(size_t)n * NN + m]) * v3[b * NN + m];
            part += fabsf(fdir - find);
        }
    }
    #pragma unroll
    for (int o = 32; o >= 1; o >>= 1) part += __shfl_xor(part, o, 64);
    int wave = tid >> 6, lane = tid & 63;
    if (lane == 0) red[wave] = part;
    __syncthreads();
    if (tid == 0){
        float s = red[0] + red[1] + red[2] + red[3];
        atomicAdd(accum, s);
    }
}

// ---------------- finalize: mean ------------------------------------------------------------
__global__ void fin_k(const float* __restrict__ accum, float* __restrict__ out){
    out[0] = accum[0] * (1.0f / 16777216.0f);   // / (B*N*N)
}

extern "C" void kernel_launch(void* const* d_in, const int* in_sizes, int n_in,
                              void* d_out, int out_size, void* d_ws, size_t ws_size,
                              hipStream_t stream){
    const float* fs = (const float*)d_in[0];
    const float* ft = (const float*)d_in[1];
    const float* fg = (const float*)d_in[2];
    float* out = (float*)d_out;
    char* ws = (char*)d_ws;

    size_t o = 0;
    u16* K1 = (u16*)(ws + o); o += (size_t)BB * NM * sizeof(u16);   // 33.5 MB each
    u16* K2 = (u16*)(ws + o); o += (size_t)BB * NM * sizeof(u16);
    u16* K3 = (u16*)(ws + o); o += (size_t)BB * NM * sizeof(u16);
    float* xs = (float*)(ws + o); o += (size_t)BB * NN * DD * sizeof(float);
    float* xt = (float*)(ws + o); o += (size_t)BB * NN * DD * sizeof(float);
    float* xg = (float*)(ws + o); o += (size_t)BB * NN * DD * sizeof(float);
    float* u1 = (float*)(ws + o); o += (size_t)BB * NN * sizeof(float);
    float* v1 = (float*)(ws + o); o += (size_t)BB * NN * sizeof(float);
    float* u2 = (float*)(ws + o); o += (size_t)BB * NN * sizeof(float);
    float* v2 = (float*)(ws + o); o += (size_t)BB * NN * sizeof(float);
    float* u3 = (float*)(ws + o); o += (size_t)BB * NN * sizeof(float);
    float* v3 = (float*)(ws + o); o += (size_t)BB * NN * sizeof(float);
    float* wv = (float*)(ws + o); o += (size_t)BB * NN * sizeof(float);
    float* t0 = (float*)(ws + o); o += (size_t)BB * NN * sizeof(float);
    float* t1 = (float*)(ws + o); o += (size_t)BB * NN * sizeof(float);
    float* accum = (float*)(ws + o); o += 256;
    // total ~107 MB of ws

    // 1) normalize features
    norm_k<<<BB * NN / 4, 256, 0, stream>>>(fs, xs);
    norm_k<<<BB * NN / 4, 256, 0, stream>>>(ft, xt);
    norm_k<<<BB * NN / 4, 256, 0, stream>>>(fg, xg);

    // 2) Gibbs kernels
    dim3 gg(32, 32, BB), gb(16, 16);
    gibbs_k<<<gg, gb, 0, stream>>>(xs, xt, K1);
    gibbs_k<<<gg, gb, 0, stream>>>(xt, xg, K2);
    gibbs_k<<<gg, gb, 0, stream>>>(xs, xg, K3);

    // 3) init
    init_k<<<BB * NN / 256, 256, 0, stream>>>(u1, u2, u3, t0, t1, accum);

    // 4) Sinkhorn (double-buffered t; rowsum_k zeroes the next t buffer)
    float* tb[2] = { t0, t1 };
    const u16* Ks[3] = { K1, K2, K3 };
    float* us[3] = { u1, u2, u3 };
    float* vs[3] = { v1, v2, v3 };
    for (int q = 0; q < 3; q++){
        for (int it = 0; it < ITERS; it++){
            colsum_k<<<dim3(BB, NN / 256, 32), 256, 0, stream>>>(Ks[q], us[q], tb[it & 1]);
            rowsum_k<<<dim3(BB, NN / 4), 256, 0, stream>>>(Ks[q], tb[it & 1], us[q], vs[q],
                                                           tb[(it + 1) & 1]);
        }
    }

    // 5) w = v1 * u2
    w_k<<<BB * NN / 256, 256, 0, stream>>>(v1, u2, wv);

    // 6) fused GEMM + |diff| reduction
    fgemm_k<<<dim3(32, 32, BB), gb, 0, stream>>>(K1, K2, K3, wv, u1, v2, u3, v3, accum);

    // 7) finalize mean
    fin_k<<<1, 1, 0, stream>>>(accum, out);
}

// Round 3
// 695.662 us; speedup vs baseline: 3.4011x; 3.4011x over previous
//
#include <hip/hip_runtime.h>
#include <hip/hip_bf16.h>
#include <math.h>

#define BB 4
#define NN 2048
#define DD 64
#define NM (NN*NN)
#define ITERS 5                       // contraction fi^2 ~ 1e-4/iter: fully converged
#define FI 0.009900990099009901f      // tau/(tau+eps)
#define MU (1.0f/2048.0f)
#define LN_MU (-7.6246189766838976f)  // ln(1/2048) = -11*ln2
#define EPS_DEN 1e-30f

typedef unsigned short u16;
typedef __attribute__((ext_vector_type(8))) short short8;
typedef __attribute__((ext_vector_type(8))) short bf16x8;
typedef __attribute__((ext_vector_type(4))) float f32x4;

static __device__ __forceinline__ float bf2f(u16 x){
    unsigned int u = ((unsigned int)x) << 16;
    return __uint_as_float(u);
}
static __device__ __forceinline__ u16 f2bf(float f){
    unsigned int u = __float_as_uint(f);
    unsigned int r = (u + 0x7FFFu + ((u >> 16) & 1u)) >> 16;
    return (u16)r;
}
// y = (MU/(t+eps))^FI via hw exp/log
static __device__ __forceinline__ float powfi(float t){
    return __expf(FI * (LN_MU - __logf(t + EPS_DEN)));
}

// ---------------- normalize ----------------
__global__ void norm_k(const float* __restrict__ x, float* __restrict__ xn){
    int row  = blockIdx.x * 4 + (threadIdx.x >> 6);
    int lane = threadIdx.x & 63;
    float v = x[row * DD + lane];
    float ss = v * v;
    #pragma unroll
    for (int o = 32; o >= 1; o >>= 1) ss += __shfl_xor(ss, o, 64);
    float s = 1.0f / (sqrtf(ss) + 1e-8f);
    xn[row * DD + lane] = v * s;
}

// ---------------- Gibbs: K[b,n,m] = exp(10*dot(A_n,B_m) - 10), bf16 ----------------
__global__ void gibbs_k(const float* __restrict__ A, const float* __restrict__ Bm,
                        u16* __restrict__ K){
    __shared__ float As[64][65];
    __shared__ float Bs[64][65];
    int b  = blockIdx.z;
    int n0 = blockIdx.y * 64, m0 = blockIdx.x * 64;
    int tx = threadIdx.x, ty = threadIdx.y;
    int tid = ty * 16 + tx;
    const float* Ab = A + ((size_t)b * NN + n0) * DD;
    const float* Bb = Bm + ((size_t)b * NN + m0) * DD;
    #pragma unroll
    for (int i = 0; i < 16; i++){
        int lin = tid + 256 * i;
        int r = lin >> 6, c = lin & 63;
        As[r][c] = Ab[r * DD + c];
        Bs[r][c] = Bb[r * DD + c];
    }
    __syncthreads();
    float acc[4][4] = {};
    #pragma unroll
    for (int k = 0; k < 64; k++){
        float a[4], bv[4];
        #pragma unroll
        for (int i = 0; i < 4; i++) a[i]  = As[ty * 4 + i][k];
        #pragma unroll
        for (int j = 0; j < 4; j++) bv[j] = Bs[tx * 4 + j][k];
        #pragma unroll
        for (int i = 0; i < 4; i++)
            #pragma unroll
            for (int j = 0; j < 4; j++)
                acc[i][j] = fmaf(a[i], bv[j], acc[i][j]);
    }
    u16* Kb = K + (size_t)b * NM;
    #pragma unroll
    for (int i = 0; i < 4; i++){
        int n = n0 + ty * 4 + i;
        #pragma unroll
        for (int j = 0; j < 4; j++){
            int m = m0 + tx * 4 + j;
            float kv = __expf(fmaf(10.0f, acc[i][j], -10.0f));
            Kb[(size_t)n * NN + m] = f2bf(kv);
        }
    }
}

// ---------------- init ----------------
__global__ void init_k(float* u1, float* u3, float* t0, float* t1, float* accum){
    int i = blockIdx.x * 256 + threadIdx.x;   // 8192
    u1[i] = 1.0f; u3[i] = 1.0f;
    t0[i] = 0.0f; t1[i] = 0.0f;
    if (i == 0) accum[0] = 0.0f;
}

// ---------------- colsum: t[c] += sum_r K[r,c]*x[r] (chunked, atomic) ----------------
__global__ void csum_k(const u16* __restrict__ K, const float* __restrict__ x,
                       float* __restrict__ t){
    // grid (BB, 64) : 32-row chunks; block 256; thread owns 8 consecutive cols
    int b = blockIdx.x;
    int r0 = blockIdx.y * 32;
    int c0 = threadIdx.x * 8;
    const u16* Kp = K + ((size_t)b * NN + r0) * NN + c0;
    const float* xb = x + b * NN + r0;
    float acc[8] = {};
    #pragma unroll 4
    for (int r = 0; r < 32; r++){
        short8 kv = *reinterpret_cast<const short8*>(Kp + (size_t)r * NN);
        float xv = xb[r];
        #pragma unroll
        for (int j = 0; j < 8; j++) acc[j] = fmaf(bf2f((u16)kv[j]), xv, acc[j]);
    }
    #pragma unroll
    for (int j = 0; j < 8; j++) atomicAdd(&t[b * NN + c0 + j], acc[j]);
}

// ---- fused: y = pow(t) (or 1); store y->outY (rg==0), zero tzero (rg==0);
//      per row r: outR[r] = pow(mu/(dot(K[r,:],y)+eps)) ------------------------------
__global__ void rsum_k(const u16* __restrict__ K, const float* __restrict__ t,
                       float* __restrict__ outY, float* __restrict__ outR,
                       float* __restrict__ tzero, int unit_y){
    // grid (BB, 128), block 256: 4 waves x 4 rows = 16 rows/block
    __shared__ float ysh[NN];
    int b = blockIdx.x, rg = blockIdx.y;
    int tid = threadIdx.x;
    const float* tb = t + b * NN;
    for (int m = tid; m < NN; m += 256)
        ysh[m] = unit_y ? 1.0f : powfi(tb[m]);
    __syncthreads();
    if (rg == 0){
        for (int m = tid; m < NN; m += 256){
            outY[b * NN + m] = ysh[m];
            tzero[b * NN + m] = 0.0f;
        }
    }
    int wave = tid >> 6, lane = tid & 63;
    int rsub = lane >> 4, l16 = lane & 15;
    int r = rg * 16 + wave * 4 + rsub;
    const u16* Kp = K + ((size_t)b * NN + r) * NN;
    float acc = 0.0f;
    #pragma unroll 4
    for (int c = 0; c < 16; c++){
        int m = c * 128 + l16 * 8;
        short8 kv = *reinterpret_cast<const short8*>(Kp + m);
        f32x4 y0 = *reinterpret_cast<const f32x4*>(&ysh[m]);
        f32x4 y1 = *reinterpret_cast<const f32x4*>(&ysh[m + 4]);
        acc = fmaf(bf2f((u16)kv[0]), y0.x, acc);
        acc = fmaf(bf2f((u16)kv[1]), y0.y, acc);
        acc = fmaf(bf2f((u16)kv[2]), y0.z, acc);
        acc = fmaf(bf2f((u16)kv[3]), y0.w, acc);
        acc = fmaf(bf2f((u16)kv[4]), y1.x, acc);
        acc = fmaf(bf2f((u16)kv[5]), y1.y, acc);
        acc = fmaf(bf2f((u16)kv[6]), y1.z, acc);
        acc = fmaf(bf2f((u16)kv[7]), y1.w, acc);
    }
    acc += __shfl_xor(acc, 1, 64);
    acc += __shfl_xor(acc, 2, 64);
    acc += __shfl_xor(acc, 4, 64);
    acc += __shfl_xor(acc, 8, 64);
    if (l16 == 0) outR[b * NN + r] = powfi(acc);
}

// ---------------- in-place scale: K1[b,n,k] *= v1[b,k]*u2[b,k], bf16 ----------------
__global__ void scale_k(u16* __restrict__ K1, const float* __restrict__ v1,
                        const float* __restrict__ u2){
    size_t i = ((size_t)blockIdx.x * 256 + threadIdx.x) * 8;
    int k = (int)(i & (NN - 1));
    int b = (int)(i >> 22);
    short8 kv = *reinterpret_cast<const short8*>(K1 + i);
    const float* vv = v1 + b * NN + k;
    const float* uu = u2 + b * NN + k;
    #pragma unroll
    for (int j = 0; j < 8; j++){
        float w = vv[j] * uu[j];
        kv[j] = (short)f2bf(bf2f((u16)kv[j]) * w);
    }
    *reinterpret_cast<short8*>(K1 + i) = kv;
}

// ---------------- MFMA fused final GEMM + |diff| reduce ----------------
// C[n,m] = sum_k A[n,k]*BT[m,k];  part = sum |u3 K3 v3 - u1 C v2|
__global__ __launch_bounds__(256) void fgemm_k(
        const u16* __restrict__ A, const u16* __restrict__ BT,
        const u16* __restrict__ K3,
        const float* __restrict__ u1, const float* __restrict__ v2,
        const float* __restrict__ u3, const float* __restrict__ v3,
        float* __restrict__ accum){
    __shared__ __align__(16) u16 As[128 * 32];
    __shared__ __align__(16) u16 Bs[128 * 32];
    __shared__ float red[4];
    int b  = blockIdx.z;
    int n0 = blockIdx.y * 128, m0 = blockIdx.x * 128;
    int tid = threadIdx.x;
    int wave = tid >> 6, lane = tid & 63;
    int wr = wave >> 1, wc = wave & 1;          // 2x2 waves, 64x64 out each
    const u16* Ab = A  + (size_t)b * NM;
    const u16* Bb = BT + (size_t)b * NM;

    // staging: chunk q (16B) -> tile row q>>2, k-off (q&3)*8; LDS linear
    int sr0 = tid >> 2,           sc = (tid & 3) << 3;
    int sr1 = (tid + 256) >> 2;
    u16* lA0 = As + (size_t)(wave * 64) * 8;          // + lane*16B by HW
    u16* lA1 = As + (size_t)(wave * 64 + 256) * 8;
    u16* lB0 = Bs + (size_t)(wave * 64) * 8;
    u16* lB1 = Bs + (size_t)(wave * 64 + 256) * 8;

    f32x4 acc[4][4] = {};
    int l16 = lane & 15, lk = (lane >> 4) * 8;
    const u16* arb = As + ((size_t)(wr * 64 + l16)) * 32 + lk;
    const u16* brb = Bs + ((size_t)(wc * 64 + l16)) * 32 + lk;

    for (int k0 = 0; k0 < NN; k0 += 32){
        __syncthreads();
        __builtin_amdgcn_global_load_lds(
            (const __attribute__((address_space(1))) void*)(Ab + (size_t)(n0 + sr0) * NN + k0 + sc),
            (__attribute__((address_space(3))) void*)lA0, 16, 0, 0);
        __builtin_amdgcn_global_load_lds(
            (const __attribute__((address_space(1))) void*)(Ab + (size_t)(n0 + sr1) * NN + k0 + sc),
            (__attribute__((address_space(3))) void*)lA1, 16, 0, 0);
        __builtin_amdgcn_global_load_lds(
            (const __attribute__((address_space(1))) void*)(Bb + (size_t)(m0 + sr0) * NN + k0 + sc),
            (__attribute__((address_space(3))) void*)lB0, 16, 0, 0);
        __builtin_amdgcn_global_load_lds(
            (const __attribute__((address_space(1))) void*)(Bb + (size_t)(m0 + sr1) * NN + k0 + sc),
            (__attribute__((address_space(3))) void*)lB1, 16, 0, 0);
        __syncthreads();
        bf16x8 af[4], bfr[4];
        #pragma unroll
        for (int i = 0; i < 4; i++) af[i]  = *reinterpret_cast<const bf16x8*>(arb + i * 512);
        #pragma unroll
        for (int j = 0; j < 4; j++) bfr[j] = *reinterpret_cast<const bf16x8*>(brb + j * 512);
        #pragma unroll
        for (int i = 0; i < 4; i++)
            #pragma unroll
            for (int j = 0; j < 4; j++)
                acc[i][j] = __builtin_amdgcn_mfma_f32_16x16x32_bf16(af[i], bfr[j], acc[i][j], 0, 0, 0);
    }

    // epilogue: |u3*K3*v3 - u1*C*v2|
    const u16* K3b = K3 + (size_t)b * NM;
    int rbase = (lane >> 4) * 4;
    float part = 0.0f;
    #pragma unroll
    for (int i = 0; i < 4; i++){
        #pragma unroll
        for (int r = 0; r < 4; r++){
            int n = n0 + wr * 64 + i * 16 + rbase + r;
            float u1n = u1[b * NN + n], u3n = u3[b * NN + n];
            const u16* k3row = K3b + (size_t)n * NN + m0 + wc * 64 + l16;
            #pragma unroll
            for (int j = 0; j < 4; j++){
                int m = m0 + wc * 64 + j * 16 + l16;
                float find = u1n * acc[i][j][r] * v2[b * NN + m];
                float fdir = u3n * bf2f(k3row[j * 16]) * v3[b * NN + m];
                part += fabsf(fdir - find);
            }
        }
    }
    #pragma unroll
    for (int o = 32; o >= 1; o >>= 1) part += __shfl_xor(part, o, 64);
    if (lane == 0) red[wave] = part;
    __syncthreads();
    if (tid == 0) atomicAdd(accum, red[0] + red[1] + red[2] + red[3]);
}

__global__ void fin_k(const float* __restrict__ accum, float* __restrict__ out){
    out[0] = accum[0] * (1.0f / 16777216.0f);
}

extern "C" void kernel_launch(void* const* d_in, const int* in_sizes, int n_in,
                              void* d_out, int out_size, void* d_ws, size_t ws_size,
                              hipStream_t stream){
    const float* fs = (const float*)d_in[0];
    const float* ft = (const float*)d_in[1];
    const float* fg = (const float*)d_in[2];
    float* out = (float*)d_out;
    char* ws = (char*)d_ws;

    size_t o = 0;
    u16* K1  = (u16*)(ws + o); o += (size_t)BB * NM * sizeof(u16);
    u16* K2T = (u16*)(ws + o); o += (size_t)BB * NM * sizeof(u16);  // [gen][tgt]
    u16* K3  = (u16*)(ws + o); o += (size_t)BB * NM * sizeof(u16);
    float* xs = (float*)(ws + o); o += (size_t)BB * NN * DD * sizeof(float);
    float* xt = (float*)(ws + o); o += (size_t)BB * NN * DD * sizeof(float);
    float* xg = (float*)(ws + o); o += (size_t)BB * NN * DD * sizeof(float);
    float* u1 = (float*)(ws + o); o += (size_t)BB * NN * sizeof(float);
    float* v1 = (float*)(ws + o); o += (size_t)BB * NN * sizeof(float);
    float* u2 = (float*)(ws + o); o += (size_t)BB * NN * sizeof(float);
    float* v2 = (float*)(ws + o); o += (size_t)BB * NN * sizeof(float);
    float* u3 = (float*)(ws + o); o += (size_t)BB * NN * sizeof(float);
    float* v3 = (float*)(ws + o); o += (size_t)BB * NN * sizeof(float);
    float* t0 = (float*)(ws + o); o += (size_t)BB * NN * sizeof(float);
    float* t1 = (float*)(ws + o); o += (size_t)BB * NN * sizeof(float);
    float* accum = (float*)(ws + o); o += 256;

    norm_k<<<BB * NN / 4, 256, 0, stream>>>(fs, xs);
    norm_k<<<BB * NN / 4, 256, 0, stream>>>(ft, xt);
    norm_k<<<BB * NN / 4, 256, 0, stream>>>(fg, xg);

    dim3 gg(32, 32, BB), gb(16, 16);
    gibbs_k<<<gg, gb, 0, stream>>>(xs, xt, K1);    // K1 [src][tgt]
    gibbs_k<<<gg, gb, 0, stream>>>(xg, xt, K2T);   // K2T[gen][tgt] = K2^T
    gibbs_k<<<gg, gb, 0, stream>>>(xs, xg, K3);    // K3 [src][gen]

    init_k<<<BB * NN / 256, 256, 0, stream>>>(u1, u3, t0, t1, accum);

    dim3 cg(BB, 64), rg(BB, 128);
    float* tb[2] = { t0, t1 };

    // uot1: colsum-first on K1 (u over rows/src, v over cols/tgt)
    for (int it = 0; it < ITERS; it++){
        csum_k<<<cg, 256, 0, stream>>>(K1, u1, tb[it & 1]);
        rsum_k<<<rg, 256, 0, stream>>>(K1, tb[it & 1], v1, u1, tb[(it + 1) & 1], 0);
    }
    // end: t1 zeroed, t0 dirty

    // uot2: rowsum-first on K2T (u2 over tgt = cols of K2T, v2 over gen = rows)
    rsum_k<<<rg, 256, 0, stream>>>(K2T, t1, u2, v2, t0, 1);   // y=1 (=u2), v2=rows; zero t0
    for (int it = 0; it < ITERS; it++){
        csum_k<<<cg, 256, 0, stream>>>(K2T, v2, tb[it & 1]);
        rsum_k<<<rg, 256, 0, stream>>>(K2T, tb[it & 1], u2, v2, tb[(it + 1) & 1], 0);
    }
    // end: t1 zeroed, t0 dirty

    // uot3: colsum-first on K3, starting with the zeroed t1
    for (int it = 0; it < ITERS; it++){
        csum_k<<<cg, 256, 0, stream>>>(K3, u3, tb[(it & 1) ^ 1]);
        rsum_k<<<rg, 256, 0, stream>>>(K3, tb[(it & 1) ^ 1], v3, u3, tb[it & 1], 0);
    }

    // K1 <- K1 * diag(v1*u2)
    scale_k<<<(BB * NM / 8) / 256, 256, 0, stream>>>(K1, v1, u2);

    // fused MFMA GEMM + |diff|
    fgemm_k<<<dim3(16, 16, BB), 256, 0, stream>>>(K1, K2T, K3, u1, v2, u3, v3, accum);

    fin_k<<<1, 1, 0, stream>>>(accum, out);
}

// Round 4
// 400.256 us; speedup vs baseline: 5.9112x; 1.7380x over previous
//
#include <hip/hip_runtime.h>
#include <hip/hip_bf16.h>
#include <math.h>

#define BB 4
#define NN 2048
#define DD 64
#define NM (NN*NN)
#define ITERS 2                       // fi^4 ~ 1e-8: converged below fp32 eps
#define FI 0.009900990099009901f      // tau/(tau+eps)
#define LN_MU (-7.6246189766838976f)  // ln(1/2048)
#define EPS_DEN 1e-30f

typedef unsigned short u16;
typedef __attribute__((ext_vector_type(8))) short short8;
typedef __attribute__((ext_vector_type(8))) short bf16x8;
typedef __attribute__((ext_vector_type(4))) float f32x4;

static __device__ __forceinline__ float bf2f(u16 x){
    unsigned int u = ((unsigned int)x) << 16;
    return __uint_as_float(u);
}
static __device__ __forceinline__ u16 f2bf(float f){
    unsigned int u = __float_as_uint(f);
    unsigned int r = (u + 0x7FFFu + ((u >> 16) & 1u)) >> 16;
    return (u16)r;
}
// (MU/(t+eps))^FI via hw exp/log
static __device__ __forceinline__ float powfi(float t){
    return __expf(FI * (LN_MU - __logf(t + EPS_DEN)));
}

// ---- Gibbs + fused normalize: K[q,b,n,m] = exp(10*cos(A_n,B_m) - 10), bf16 ----
// q=0: (fs,ft)->K1[src][tgt]; q=1: (fg,ft)->K2T[gen][tgt]; q=2: (fs,fg)->K3[src][gen]
__global__ void gibbs_all(const float* __restrict__ fs, const float* __restrict__ ft,
                          const float* __restrict__ fg, u16* __restrict__ Kbase){
    __shared__ float As[64][65];
    __shared__ float Bs[64][65];
    __shared__ float ainv[64], binv[64];
    int zz = blockIdx.z;                 // 0..11
    int q = zz >> 2, b = zz & 3;
    const float* A  = (q == 1) ? fg : fs;
    const float* Bm = (q == 2) ? fg : ft;
    u16* K = Kbase + ((size_t)q * BB + b) * NM;
    int n0 = blockIdx.y * 64, m0 = blockIdx.x * 64;
    int tx = threadIdx.x, ty = threadIdx.y;
    int tid = ty * 16 + tx;
    const float* Ab = A  + ((size_t)b * NN + n0) * DD;
    const float* Bb = Bm + ((size_t)b * NN + m0) * DD;
    #pragma unroll
    for (int i = 0; i < 16; i++){
        int lin = tid + 256 * i;
        int r = lin >> 6, c = lin & 63;
        As[r][c] = Ab[r * DD + c];
        Bs[r][c] = Bb[r * DD + c];
    }
    __syncthreads();
    if (tid < 128){
        int r = tid & 63;
        const float* row = (tid < 64) ? &As[r][0] : &Bs[r][0];
        float ss = 0.0f;
        #pragma unroll
        for (int k = 0; k < 64; k++){ float v = row[k]; ss = fmaf(v, v, ss); }
        float inv = 1.0f / (sqrtf(ss) + 1e-8f);
        if (tid < 64) ainv[r] = inv; else binv[r] = inv;
    }
    __syncthreads();
    float acc[4][4] = {};
    #pragma unroll
    for (int k = 0; k < 64; k++){
        float a[4], bv[4];
        #pragma unroll
        for (int i = 0; i < 4; i++) a[i]  = As[ty * 4 + i][k];
        #pragma unroll
        for (int j = 0; j < 4; j++) bv[j] = Bs[tx * 4 + j][k];
        #pragma unroll
        for (int i = 0; i < 4; i++)
            #pragma unroll
            for (int j = 0; j < 4; j++)
                acc[i][j] = fmaf(a[i], bv[j], acc[i][j]);
    }
    #pragma unroll
    for (int i = 0; i < 4; i++){
        int n = n0 + ty * 4 + i;
        float ai = ainv[ty * 4 + i];
        #pragma unroll
        for (int j = 0; j < 4; j++){
            int m = m0 + tx * 4 + j;
            float cosv = acc[i][j] * ai * binv[tx * 4 + j];
            float kv = __expf(fmaf(10.0f, cosv, -10.0f));
            K[(size_t)n * NN + m] = f2bf(kv);
        }
    }
}

// ---- init: R=1 (rowvecs u1,v2,u3), T0=T1=0, accum=0 ----
__global__ void init_k(float* R, float* T0, float* T1, float* accum){
    int i = blockIdx.x * 256 + threadIdx.x;   // 3*8192 = 24576
    R[i] = 1.0f; T0[i] = 0.0f; T1[i] = 0.0f;
    if (i == 0) accum[0] = 0.0f;
}

// ---- merged colsum: T[z,b,c] += sum_r K[z,b,r,c] * R[z,b,r]  (32-row chunks) ----
__global__ void csum_all(const u16* __restrict__ Kbase, const float* __restrict__ R,
                         float* __restrict__ T){
    int b = blockIdx.x, z = blockIdx.z;
    int r0 = blockIdx.y * 32;
    int c0 = threadIdx.x * 8;
    const u16* Kp = Kbase + (size_t)z * BB * NM + ((size_t)b * NN + r0) * NN + c0;
    const float* xb = R + ((size_t)z * BB + b) * NN + r0;
    float acc[8] = {};
    #pragma unroll 4
    for (int r = 0; r < 32; r++){
        short8 kv = *reinterpret_cast<const short8*>(Kp + (size_t)r * NN);
        float xv = xb[r];
        #pragma unroll
        for (int j = 0; j < 8; j++) acc[j] = fmaf(bf2f((u16)kv[j]), xv, acc[j]);
    }
    float* tp = T + ((size_t)z * BB + b) * NN + c0;
    #pragma unroll
    for (int j = 0; j < 8; j++) atomicAdd(&tp[j], acc[j]);
}

// ---- merged: colvec y = pow(T) -> Cv (rg==0 stores, zeroes Tnext);
//      rowvec R[r] = pow(mu/(dot(K[r,:], y)+eps)) ; 32 rows per block ----
__global__ void rsum_all(const u16* __restrict__ Kbase, const float* __restrict__ T,
                         float* __restrict__ Cv, float* __restrict__ R,
                         float* __restrict__ Tnext){
    __shared__ float ysh[NN];
    int b = blockIdx.x, rg = blockIdx.y, z = blockIdx.z;
    int tid = threadIdx.x;
    const float* tb = T + ((size_t)z * BB + b) * NN;
    for (int m = tid; m < NN; m += 256)
        ysh[m] = powfi(tb[m]);
    __syncthreads();
    if (rg == 0){
        float* cvp = Cv + ((size_t)z * BB + b) * NN;
        float* tzp = Tnext + ((size_t)z * BB + b) * NN;
        for (int m = tid; m < NN; m += 256){
            cvp[m] = ysh[m];
            tzp[m] = 0.0f;
        }
    }
    int wave = tid >> 6, lane = tid & 63;
    int rsub = lane >> 4, l16 = lane & 15;
    int g = wave * 4 + rsub;                   // 0..15
    const u16* Kz = Kbase + (size_t)z * BB * NM + (size_t)b * NN * NN;
    float* Rp = R + ((size_t)z * BB + b) * NN;
    #pragma unroll
    for (int h = 0; h < 2; h++){
        int r = rg * 32 + h * 16 + g;
        const u16* Kp = Kz + (size_t)r * NN;
        float acc = 0.0f;
        #pragma unroll 4
        for (int c = 0; c < 16; c++){
            int m = c * 128 + l16 * 8;
            short8 kv = *reinterpret_cast<const short8*>(Kp + m);
            f32x4 y0 = *reinterpret_cast<const f32x4*>(&ysh[m]);
            f32x4 y1 = *reinterpret_cast<const f32x4*>(&ysh[m + 4]);
            acc = fmaf(bf2f((u16)kv[0]), y0.x, acc);
            acc = fmaf(bf2f((u16)kv[1]), y0.y, acc);
            acc = fmaf(bf2f((u16)kv[2]), y0.z, acc);
            acc = fmaf(bf2f((u16)kv[3]), y0.w, acc);
            acc = fmaf(bf2f((u16)kv[4]), y1.x, acc);
            acc = fmaf(bf2f((u16)kv[5]), y1.y, acc);
            acc = fmaf(bf2f((u16)kv[6]), y1.z, acc);
            acc = fmaf(bf2f((u16)kv[7]), y1.w, acc);
        }
        acc += __shfl_xor(acc, 1, 64);
        acc += __shfl_xor(acc, 2, 64);
        acc += __shfl_xor(acc, 4, 64);
        acc += __shfl_xor(acc, 8, 64);
        if (l16 == 0) Rp[r] = powfi(acc);
    }
}

// ---- in-place scale: K1[b,n,k] *= v1[b,k]*u2[b,k], bf16 ----
__global__ void scale_k(u16* __restrict__ K1, const float* __restrict__ v1,
                        const float* __restrict__ u2){
    size_t i = ((size_t)blockIdx.x * 256 + threadIdx.x) * 8;
    int k = (int)(i & (NN - 1));
    int b = (int)(i >> 22);
    short8 kv = *reinterpret_cast<const short8*>(K1 + i);
    const float* vv = v1 + b * NN + k;
    const float* uu = u2 + b * NN + k;
    #pragma unroll
    for (int j = 0; j < 8; j++){
        float w = vv[j] * uu[j];
        kv[j] = (short)f2bf(bf2f((u16)kv[j]) * w);
    }
    *reinterpret_cast<short8*>(K1 + i) = kv;
}

// ---- MFMA fused final GEMM + |diff| reduce ----
__global__ __launch_bounds__(256) void fgemm_k(
        const u16* __restrict__ A, const u16* __restrict__ BT,
        const u16* __restrict__ K3,
        const float* __restrict__ u1, const float* __restrict__ v2,
        const float* __restrict__ u3, const float* __restrict__ v3,
        float* __restrict__ accum){
    __shared__ __align__(16) u16 As[128 * 32];
    __shared__ __align__(16) u16 Bs[128 * 32];
    __shared__ float red[4];
    int b  = blockIdx.z;
    int n0 = blockIdx.y * 128, m0 = blockIdx.x * 128;
    int tid = threadIdx.x;
    int wave = tid >> 6, lane = tid & 63;
    int wr = wave >> 1, wc = wave & 1;
    const u16* Ab = A  + (size_t)b * NM;
    const u16* Bb = BT + (size_t)b * NM;

    int sr0 = tid >> 2,           sc = (tid & 3) << 3;
    int sr1 = (tid + 256) >> 2;
    u16* lA0 = As + (size_t)(wave * 64) * 8;
    u16* lA1 = As + (size_t)(wave * 64 + 256) * 8;
    u16* lB0 = Bs + (size_t)(wave * 64) * 8;
    u16* lB1 = Bs + (size_t)(wave * 64 + 256) * 8;

    f32x4 acc[4][4] = {};
    int l16 = lane & 15, lk = (lane >> 4) * 8;
    const u16* arb = As + ((size_t)(wr * 64 + l16)) * 32 + lk;
    const u16* brb = Bs + ((size_t)(wc * 64 + l16)) * 32 + lk;

    for (int k0 = 0; k0 < NN; k0 += 32){
        __syncthreads();
        __builtin_amdgcn_global_load_lds(
            (const __attribute__((address_space(1))) void*)(Ab + (size_t)(n0 + sr0) * NN + k0 + sc),
            (__attribute__((address_space(3))) void*)lA0, 16, 0, 0);
        __builtin_amdgcn_global_load_lds(
            (const __attribute__((address_space(1))) void*)(Ab + (size_t)(n0 + sr1) * NN + k0 + sc),
            (__attribute__((address_space(3))) void*)lA1, 16, 0, 0);
        __builtin_amdgcn_global_load_lds(
            (const __attribute__((address_space(1))) void*)(Bb + (size_t)(m0 + sr0) * NN + k0 + sc),
            (__attribute__((address_space(3))) void*)lB0, 16, 0, 0);
        __builtin_amdgcn_global_load_lds(
            (const __attribute__((address_space(1))) void*)(Bb + (size_t)(m0 + sr1) * NN + k0 + sc),
            (__attribute__((address_space(3))) void*)lB1, 16, 0, 0);
        __syncthreads();
        bf16x8 af[4], bfr[4];
        #pragma unroll
        for (int i = 0; i < 4; i++) af[i]  = *reinterpret_cast<const bf16x8*>(arb + i * 512);
        #pragma unroll
        for (int j = 0; j < 4; j++) bfr[j] = *reinterpret_cast<const bf16x8*>(brb + j * 512);
        #pragma unroll
        for (int i = 0; i < 4; i++)
            #pragma unroll
            for (int j = 0; j < 4; j++)
                acc[i][j] = __builtin_amdgcn_mfma_f32_16x16x32_bf16(af[i], bfr[j], acc[i][j], 0, 0, 0);
    }

    const u16* K3b = K3 + (size_t)b * NM;
    int rbase = (lane >> 4) * 4;
    float part = 0.0f;
    #pragma unroll
    for (int i = 0; i < 4; i++){
        #pragma unroll
        for (int r = 0; r < 4; r++){
            int n = n0 + wr * 64 + i * 16 + rbase + r;
            float u1n = u1[b * NN + n], u3n = u3[b * NN + n];
            const u16* k3row = K3b + (size_t)n * NN + m0 + wc * 64 + l16;
            #pragma unroll
            for (int j = 0; j < 4; j++){
                int m = m0 + wc * 64 + j * 16 + l16;
                float find = u1n * acc[i][j][r] * v2[b * NN + m];
                float fdir = u3n * bf2f(k3row[j * 16]) * v3[b * NN + m];
                part += fabsf(fdir - find);
            }
        }
    }
    #pragma unroll
    for (int o = 32; o >= 1; o >>= 1) part += __shfl_xor(part, o, 64);
    if (lane == 0) red[wave] = part;
    __syncthreads();
    if (tid == 0) atomicAdd(accum, red[0] + red[1] + red[2] + red[3]);
}

__global__ void fin_k(const float* __restrict__ accum, float* __restrict__ out){
    out[0] = accum[0] * (1.0f / 16777216.0f);
}

extern "C" void kernel_launch(void* const* d_in, const int* in_sizes, int n_in,
                              void* d_out, int out_size, void* d_ws, size_t ws_size,
                              hipStream_t stream){
    const float* fs = (const float*)d_in[0];
    const float* ft = (const float*)d_in[1];
    const float* fg = (const float*)d_in[2];
    float* out = (float*)d_out;
    char* ws = (char*)d_ws;

    size_t o = 0;
    u16* Kbase = (u16*)(ws + o); o += (size_t)3 * BB * NM * sizeof(u16);  // K1,K2T,K3 contiguous
    float* R  = (float*)(ws + o); o += (size_t)3 * BB * NN * sizeof(float); // rowvecs: u1,v2,u3
    float* Cv = (float*)(ws + o); o += (size_t)3 * BB * NN * sizeof(float); // colvecs: v1,u2,v3
    float* T0 = (float*)(ws + o); o += (size_t)3 * BB * NN * sizeof(float);
    float* T1 = (float*)(ws + o); o += (size_t)3 * BB * NN * sizeof(float);
    float* accum = (float*)(ws + o); o += 256;

    u16* K1  = Kbase;
    u16* K2T = Kbase + (size_t)BB * NM;
    u16* K3  = Kbase + (size_t)2 * BB * NM;

    // 1) Gibbs (normalize fused), all 3 kernels + 4 batches in one dispatch
    gibbs_all<<<dim3(32, 32, 12), dim3(16, 16), 0, stream>>>(fs, ft, fg, Kbase);

    // 2) init
    init_k<<<96, 256, 0, stream>>>(R, T0, T1, accum);

    // 3) Sinkhorn: all 3 uots colsum-first (unique fixed point; order-swap safe)
    float* tb[2] = { T0, T1 };
    for (int it = 0; it < ITERS; it++){
        csum_all<<<dim3(BB, 64, 3), 256, 0, stream>>>(Kbase, R, tb[it & 1]);
        rsum_all<<<dim3(BB, 64, 3), 256, 0, stream>>>(Kbase, tb[it & 1], Cv, R,
                                                      tb[(it + 1) & 1]);
    }
    // R = {u1, v2, u3}, Cv = {v1, u2, v3}

    // 4) K1 <- K1 * diag(v1*u2)
    scale_k<<<8192, 256, 0, stream>>>(K1, Cv, Cv + (size_t)BB * NN);

    // 5) fused MFMA GEMM + |diff|
    fgemm_k<<<dim3(16, 16, BB), 256, 0, stream>>>(K1, K2T, K3,
                                                  R, R + (size_t)BB * NN,
                                                  R + (size_t)2 * BB * NN,
                                                  Cv + (size_t)2 * BB * NN, accum);

    // 6) finalize
    fin_k<<<1, 1, 0, stream>>>(accum, out);
}

// Round 5
// 256.971 us; speedup vs baseline: 9.2073x; 1.5576x over previous
//
#include <hip/hip_runtime.h>
#include <hip/hip_bf16.h>
#include <math.h>

#define BB 4
#define NN 2048
#define DD 64
#define NM (NN*NN)
#define FI 0.009900990099009901f      // tau/(tau+eps)
#define LN_MU (-7.6246189766838976f)  // ln(1/2048)
#define EPS_DEN 1e-30f

typedef unsigned short u16;
typedef __attribute__((ext_vector_type(8))) short short8;
typedef __attribute__((ext_vector_type(8))) short bf16x8;
typedef __attribute__((ext_vector_type(4))) float f32x4;

static __device__ __forceinline__ float bf2f(u16 x){
    unsigned int u = ((unsigned int)x) << 16;
    return __uint_as_float(u);
}
static __device__ __forceinline__ u16 f2bf(float f){
    unsigned int u = __float_as_uint(f);
    unsigned int r = (u + 0x7FFFu + ((u >> 16) & 1u)) >> 16;
    return (u16)r;
}
// (MU/(t+eps))^FI via hw exp/log
static __device__ __forceinline__ float powfi(float t){
    return __expf(FI * (LN_MU - __logf(t + EPS_DEN)));
}

// ---- prep: bf16 cast of raw features + fp32 row inverse norms ----
// rows 0..8191 = fs, 8192..16383 = ft, 16384..24575 = fg
__global__ void norm_prep(const float* __restrict__ fs, const float* __restrict__ ft,
                          const float* __restrict__ fg,
                          u16* __restrict__ xb, float* __restrict__ rinv){
    int g    = blockIdx.x * 4 + (threadIdx.x >> 6);   // 0..24575
    int lane = threadIdx.x & 63;
    int a = g >> 13;
    int row = g & 8191;
    const float* src = (a == 0) ? fs : (a == 1) ? ft : fg;
    float v = src[row * DD + lane];
    float ss = v * v;
    #pragma unroll
    for (int o = 32; o >= 1; o >>= 1) ss += __shfl_xor(ss, o, 64);
    xb[(size_t)g * DD + lane] = f2bf(v);
    if (lane == 0) rinv[g] = 1.0f / (sqrtf(ss) + 1e-8f);
}

// ---- init: zero T0, T1, accum ----
__global__ void init_k(float* T0, float* T1, float* accum){
    int i = blockIdx.x * 256 + threadIdx.x;   // 3*8192 = 24576
    T0[i] = 0.0f; T1[i] = 0.0f;
    if (i == 0) accum[0] = 0.0f;
}

// ---- MFMA Gibbs + fused first colsum ----
// K[q,b,n,m] = exp(10*dot(A_n,B_m)*ainv_n*binv_m - 10) (bf16);
// T0[q,b,m] += colsums (fp32, atomics)  == K^T * 1
// q=0: A=xs,B=xt (K1); q=1: A=xg,B=xt (K2T); q=2: A=xs,B=xg (K3)
__global__ __launch_bounds__(256) void gibbs_mfma(
        const u16* __restrict__ xb, const float* __restrict__ rinv,
        u16* __restrict__ Kbase, float* __restrict__ T0){
    int zz = blockIdx.z;                 // 0..11
    int q = zz >> 2, b = zz & 3;
    int qa = (q == 1) ? 2 : 0;           // xs / xg / xs
    int qb = (q == 2) ? 2 : 1;           // xt / xt / xg
    const u16* Ab = xb + ((size_t)qa * BB + b) * NN * DD;
    const u16* Bb = xb + ((size_t)qb * BB + b) * NN * DD;
    const float* ainv = rinv + (size_t)qa * BB * NN + b * NN;
    const float* binv = rinv + (size_t)qb * BB * NN + b * NN;
    u16* K = Kbase + ((size_t)q * BB + b) * NM;
    float* tp = T0 + ((size_t)q * BB + b) * NN;

    int n0 = blockIdx.y * 128, m0 = blockIdx.x * 128;
    int tid = threadIdx.x;
    int wave = tid >> 6, lane = tid & 63;
    int wr = wave >> 1, wc = wave & 1;       // 2x2 waves, 64x64 out each
    int l16 = lane & 15, lk = (lane >> 4) * 8;

    // direct global fragment loads (L2-resident, fully coalesced per wave)
    bf16x8 af[4][2], bfr[4][2];
    #pragma unroll
    for (int i = 0; i < 4; i++){
        #pragma unroll
        for (int ks = 0; ks < 2; ks++){
            af[i][ks]  = *reinterpret_cast<const bf16x8*>(
                Ab + (size_t)(n0 + wr * 64 + i * 16 + l16) * DD + ks * 32 + lk);
            bfr[i][ks] = *reinterpret_cast<const bf16x8*>(
                Bb + (size_t)(m0 + wc * 64 + i * 16 + l16) * DD + ks * 32 + lk);
        }
    }
    f32x4 acc[4][4] = {};
    #pragma unroll
    for (int ks = 0; ks < 2; ks++)
        #pragma unroll
        for (int i = 0; i < 4; i++)
            #pragma unroll
            for (int j = 0; j < 4; j++)
                acc[i][j] = __builtin_amdgcn_mfma_f32_16x16x32_bf16(
                    af[i][ks], bfr[j][ks], acc[i][j], 0, 0, 0);

    // epilogue: scale by invnorms, exp, store bf16, accumulate colsums
    int rbase = (lane >> 4) * 4;
    float bi[4];
    #pragma unroll
    for (int j = 0; j < 4; j++) bi[j] = binv[m0 + wc * 64 + j * 16 + l16];
    float csum[4] = {};
    #pragma unroll
    for (int i = 0; i < 4; i++){
        #pragma unroll
        for (int r = 0; r < 4; r++){
            int n = n0 + wr * 64 + i * 16 + rbase + r;
            float ai = ainv[n];
            u16* krow = K + (size_t)n * NN + m0 + wc * 64 + l16;
            #pragma unroll
            for (int j = 0; j < 4; j++){
                float cosv = acc[i][j][r] * ai * bi[j];
                float kv = __expf(fmaf(10.0f, cosv, -10.0f));
                krow[j * 16] = f2bf(kv);
                csum[j] += kv;
            }
        }
    }
    // reduce colsums across the 4 row-subgroups (lane>>4), then atomics
    #pragma unroll
    for (int j = 0; j < 4; j++){
        csum[j] += __shfl_xor(csum[j], 16, 64);
        csum[j] += __shfl_xor(csum[j], 32, 64);
    }
    if (lane < 16){
        #pragma unroll
        for (int j = 0; j < 4; j++)
            atomicAdd(&tp[m0 + wc * 64 + j * 16 + l16], csum[j]);
    }
}

// ---- merged colsum: T[z,b,c] += sum_r K[z,b,r,c] * R[z,b,r]  (32-row chunks) ----
__global__ void csum_all(const u16* __restrict__ Kbase, const float* __restrict__ R,
                         float* __restrict__ T){
    int b = blockIdx.x, z = blockIdx.z;
    int r0 = blockIdx.y * 32;
    int c0 = threadIdx.x * 8;
    const u16* Kp = Kbase + (size_t)z * BB * NM + ((size_t)b * NN + r0) * NN + c0;
    const float* xb = R + ((size_t)z * BB + b) * NN + r0;
    float acc[8] = {};
    #pragma unroll 4
    for (int r = 0; r < 32; r++){
        short8 kv = *reinterpret_cast<const short8*>(Kp + (size_t)r * NN);
        float xv = xb[r];
        #pragma unroll
        for (int j = 0; j < 8; j++) acc[j] = fmaf(bf2f((u16)kv[j]), xv, acc[j]);
    }
    float* tp = T + ((size_t)z * BB + b) * NN + c0;
    #pragma unroll
    for (int j = 0; j < 8; j++) atomicAdd(&tp[j], acc[j]);
}

// ---- merged: colvec y = pow(T) -> Cv (rg==0 stores, zeroes Tnext);
//      rowvec R[r] = pow(mu/(dot(K[r,:], y)+eps)) ; 32 rows per block ----
__global__ void rsum_all(const u16* __restrict__ Kbase, const float* __restrict__ T,
                         float* __restrict__ Cv, float* __restrict__ R,
                         float* __restrict__ Tnext){
    __shared__ float ysh[NN];
    int b = blockIdx.x, rg = blockIdx.y, z = blockIdx.z;
    int tid = threadIdx.x;
    const float* tb = T + ((size_t)z * BB + b) * NN;
    for (int m = tid; m < NN; m += 256)
        ysh[m] = powfi(tb[m]);
    __syncthreads();
    if (rg == 0){
        float* cvp = Cv + ((size_t)z * BB + b) * NN;
        float* tzp = Tnext + ((size_t)z * BB + b) * NN;
        for (int m = tid; m < NN; m += 256){
            cvp[m] = ysh[m];
            tzp[m] = 0.0f;
        }
    }
    int wave = tid >> 6, lane = tid & 63;
    int rsub = lane >> 4, l16 = lane & 15;
    int g = wave * 4 + rsub;                   // 0..15
    const u16* Kz = Kbase + (size_t)z * BB * NM + (size_t)b * NN * NN;
    float* Rp = R + ((size_t)z * BB + b) * NN;
    #pragma unroll
    for (int h = 0; h < 2; h++){
        int r = rg * 32 + h * 16 + g;
        const u16* Kp = Kz + (size_t)r * NN;
        float acc = 0.0f;
        #pragma unroll 4
        for (int c = 0; c < 16; c++){
            int m = c * 128 + l16 * 8;
            short8 kv = *reinterpret_cast<const short8*>(Kp + m);
            f32x4 y0 = *reinterpret_cast<const f32x4*>(&ysh[m]);
            f32x4 y1 = *reinterpret_cast<const f32x4*>(&ysh[m + 4]);
            acc = fmaf(bf2f((u16)kv[0]), y0.x, acc);
            acc = fmaf(bf2f((u16)kv[1]), y0.y, acc);
            acc = fmaf(bf2f((u16)kv[2]), y0.z, acc);
            acc = fmaf(bf2f((u16)kv[3]), y0.w, acc);
            acc = fmaf(bf2f((u16)kv[4]), y1.x, acc);
            acc = fmaf(bf2f((u16)kv[5]), y1.y, acc);
            acc = fmaf(bf2f((u16)kv[6]), y1.z, acc);
            acc = fmaf(bf2f((u16)kv[7]), y1.w, acc);
        }
        acc += __shfl_xor(acc, 1, 64);
        acc += __shfl_xor(acc, 2, 64);
        acc += __shfl_xor(acc, 4, 64);
        acc += __shfl_xor(acc, 8, 64);
        if (l16 == 0) Rp[r] = powfi(acc);
    }
}

// ---- in-place scale: K1[b,n,k] *= v1[b,k]*u2[b,k], bf16 ----
__global__ void scale_k(u16* __restrict__ K1, const float* __restrict__ v1,
                        const float* __restrict__ u2){
    size_t i = ((size_t)blockIdx.x * 256 + threadIdx.x) * 8;
    int k = (int)(i & (NN - 1));
    int b = (int)(i >> 22);
    short8 kv = *reinterpret_cast<const short8*>(K1 + i);
    const float* vv = v1 + b * NN + k;
    const float* uu = u2 + b * NN + k;
    #pragma unroll
    for (int j = 0; j < 8; j++){
        float w = vv[j] * uu[j];
        kv[j] = (short)f2bf(bf2f((u16)kv[j]) * w);
    }
    *reinterpret_cast<short8*>(K1 + i) = kv;
}

// ---- MFMA fused final GEMM + |diff| reduce ----
__global__ __launch_bounds__(256) void fgemm_k(
        const u16* __restrict__ A, const u16* __restrict__ BT,
        const u16* __restrict__ K3,
        const float* __restrict__ u1, const float* __restrict__ v2,
        const float* __restrict__ u3, const float* __restrict__ v3,
        float* __restrict__ accum){
    __shared__ __align__(16) u16 As[128 * 32];
    __shared__ __align__(16) u16 Bs[128 * 32];
    __shared__ float red[4];
    int b  = blockIdx.z;
    int n0 = blockIdx.y * 128, m0 = blockIdx.x * 128;
    int tid = threadIdx.x;
    int wave = tid >> 6, lane = tid & 63;
    int wr = wave >> 1, wc = wave & 1;
    const u16* Ab = A  + (size_t)b * NM;
    const u16* Bb = BT + (size_t)b * NM;

    int sr0 = tid >> 2,           sc = (tid & 3) << 3;
    int sr1 = (tid + 256) >> 2;
    u16* lA0 = As + (size_t)(wave * 64) * 8;
    u16* lA1 = As + (size_t)(wave * 64 + 256) * 8;
    u16* lB0 = Bs + (size_t)(wave * 64) * 8;
    u16* lB1 = Bs + (size_t)(wave * 64 + 256) * 8;

    f32x4 acc[4][4] = {};
    int l16 = lane & 15, lk = (lane >> 4) * 8;
    const u16* arb = As + ((size_t)(wr * 64 + l16)) * 32 + lk;
    const u16* brb = Bs + ((size_t)(wc * 64 + l16)) * 32 + lk;

    for (int k0 = 0; k0 < NN; k0 += 32){
        __syncthreads();
        __builtin_amdgcn_global_load_lds(
            (const __attribute__((address_space(1))) void*)(Ab + (size_t)(n0 + sr0) * NN + k0 + sc),
            (__attribute__((address_space(3))) void*)lA0, 16, 0, 0);
        __builtin_amdgcn_global_load_lds(
            (const __attribute__((address_space(1))) void*)(Ab + (size_t)(n0 + sr1) * NN + k0 + sc),
            (__attribute__((address_space(3))) void*)lA1, 16, 0, 0);
        __builtin_amdgcn_global_load_lds(
            (const __attribute__((address_space(1))) void*)(Bb + (size_t)(m0 + sr0) * NN + k0 + sc),
            (__attribute__((address_space(3))) void*)lB0, 16, 0, 0);
        __builtin_amdgcn_global_load_lds(
            (const __attribute__((address_space(1))) void*)(Bb + (size_t)(m0 + sr1) * NN + k0 + sc),
            (__attribute__((address_space(3))) void*)lB1, 16, 0, 0);
        __syncthreads();
        bf16x8 af[4], bfr[4];
        #pragma unroll
        for (int i = 0; i < 4; i++) af[i]  = *reinterpret_cast<const bf16x8*>(arb + i * 512);
        #pragma unroll
        for (int j = 0; j < 4; j++) bfr[j] = *reinterpret_cast<const bf16x8*>(brb + j * 512);
        #pragma unroll
        for (int i = 0; i < 4; i++)
            #pragma unroll
            for (int j = 0; j < 4; j++)
                acc[i][j] = __builtin_amdgcn_mfma_f32_16x16x32_bf16(af[i], bfr[j], acc[i][j], 0, 0, 0);
    }

    const u16* K3b = K3 + (size_t)b * NM;
    int rbase = (lane >> 4) * 4;
    float part = 0.0f;
    #pragma unroll
    for (int i = 0; i < 4; i++){
        #pragma unroll
        for (int r = 0; r < 4; r++){
            int n = n0 + wr * 64 + i * 16 + rbase + r;
            float u1n = u1[b * NN + n], u3n = u3[b * NN + n];
            const u16* k3row = K3b + (size_t)n * NN + m0 + wc * 64 + l16;
            #pragma unroll
            for (int j = 0; j < 4; j++){
                int m = m0 + wc * 64 + j * 16 + l16;
                float find = u1n * acc[i][j][r] * v2[b * NN + m];
                float fdir = u3n * bf2f(k3row[j * 16]) * v3[b * NN + m];
                part += fabsf(fdir - find);
            }
        }
    }
    #pragma unroll
    for (int o = 32; o >= 1; o >>= 1) part += __shfl_xor(part, o, 64);
    if (lane == 0) red[wave] = part;
    __syncthreads();
    if (tid == 0) atomicAdd(accum, red[0] + red[1] + red[2] + red[3]);
}

__global__ void fin_k(const float* __restrict__ accum, float* __restrict__ out){
    out[0] = accum[0] * (1.0f / 16777216.0f);
}

extern "C" void kernel_launch(void* const* d_in, const int* in_sizes, int n_in,
                              void* d_out, int out_size, void* d_ws, size_t ws_size,
                              hipStream_t stream){
    const float* fs = (const float*)d_in[0];
    const float* ft = (const float*)d_in[1];
    const float* fg = (const float*)d_in[2];
    float* out = (float*)d_out;
    char* ws = (char*)d_ws;

    size_t o = 0;
    u16* Kbase = (u16*)(ws + o); o += (size_t)3 * BB * NM * sizeof(u16);  // K1,K2T,K3
    u16* xb    = (u16*)(ws + o); o += (size_t)3 * BB * NN * DD * sizeof(u16); // bf16 feats
    float* rinv = (float*)(ws + o); o += (size_t)3 * BB * NN * sizeof(float);
    float* R  = (float*)(ws + o); o += (size_t)3 * BB * NN * sizeof(float); // u1,v2,u3
    float* Cv = (float*)(ws + o); o += (size_t)3 * BB * NN * sizeof(float); // v1,u2,v3
    float* T0 = (float*)(ws + o); o += (size_t)3 * BB * NN * sizeof(float);
    float* T1 = (float*)(ws + o); o += (size_t)3 * BB * NN * sizeof(float);
    float* accum = (float*)(ws + o); o += 256;

    u16* K1  = Kbase;
    u16* K2T = Kbase + (size_t)BB * NM;
    u16* K3  = Kbase + (size_t)2 * BB * NM;

    // 1) zero T0/T1/accum (T0 receives gibbs colsum atomics)
    init_k<<<96, 256, 0, stream>>>(T0, T1, accum);

    // 2) bf16 features + inverse norms
    norm_prep<<<6144, 256, 0, stream>>>(fs, ft, fg, xb, rinv);

    // 3) MFMA Gibbs, first colsum fused (T0 = K^T 1 per z)
    gibbs_mfma<<<dim3(16, 16, 12), 256, 0, stream>>>(xb, rinv, Kbase, T0);

    // 4) Sinkhorn remainder: rsum, csum, rsum  (== 2 full damped iterations)
    rsum_all<<<dim3(BB, 64, 3), 256, 0, stream>>>(Kbase, T0, Cv, R, T1);
    csum_all<<<dim3(BB, 64, 3), 256, 0, stream>>>(Kbase, R, T1);
    rsum_all<<<dim3(BB, 64, 3), 256, 0, stream>>>(Kbase, T1, Cv, R, T0);
    // R = {u1, v2, u3}, Cv = {v1, u2, v3}

    // 5) K1 <- K1 * diag(v1*u2)
    scale_k<<<8192, 256, 0, stream>>>(K1, Cv, Cv + (size_t)BB * NN);

    // 6) fused MFMA GEMM + |diff|
    fgemm_k<<<dim3(16, 16, BB), 256, 0, stream>>>(K1, K2T, K3,
                                                  R, R + (size_t)BB * NN,
                                                  R + (size_t)2 * BB * NN,
                                                  Cv + (size_t)2 * BB * NN, accum);

    // 7) finalize
    fin_k<<<1, 1, 0, stream>>>(accum, out);
}

// Round 6
// 227.380 us; speedup vs baseline: 10.4055x; 1.1301x over previous
//
#include <hip/hip_runtime.h>
#include <hip/hip_bf16.h>
#include <math.h>

#define BB 4
#define NN 2048
#define DD 64
#define NM (NN*NN)
#define FI 0.009900990099009901f      // tau/(tau+eps)
#define LN_MU (-7.6246189766838976f)  // ln(1/2048)
#define EPS_DEN 1e-30f

typedef unsigned short u16;
typedef __attribute__((ext_vector_type(8))) short short8;
typedef __attribute__((ext_vector_type(8))) short bf16x8;
typedef __attribute__((ext_vector_type(4))) float f32x4;

static __device__ __forceinline__ float bf2f(u16 x){
    unsigned int u = ((unsigned int)x) << 16;
    return __uint_as_float(u);
}
static __device__ __forceinline__ u16 f2bf(float f){
    unsigned int u = __float_as_uint(f);
    unsigned int r = (u + 0x7FFFu + ((u >> 16) & 1u)) >> 16;
    return (u16)r;
}
static __device__ __forceinline__ float powfi(float t){
    return __expf(FI * (LN_MU - __logf(t + EPS_DEN)));
}

#define GLOAD16(src, dst) __builtin_amdgcn_global_load_lds( \
    (const __attribute__((address_space(1))) void*)(src),   \
    (__attribute__((address_space(3))) void*)(dst), 16, 0, 0)

// ---- prep: bf16 cast of raw features + fp32 row inverse norms ----
__global__ void norm_prep(const float* __restrict__ fs, const float* __restrict__ ft,
                          const float* __restrict__ fg,
                          u16* __restrict__ xb, float* __restrict__ rinv){
    int g    = blockIdx.x * 4 + (threadIdx.x >> 6);   // 0..24575
    int lane = threadIdx.x & 63;
    int a = g >> 13;
    int row = g & 8191;
    const float* src = (a == 0) ? fs : (a == 1) ? ft : fg;
    float v = src[row * DD + lane];
    float ss = v * v;
    #pragma unroll
    for (int o = 32; o >= 1; o >>= 1) ss += __shfl_xor(ss, o, 64);
    xb[(size_t)g * DD + lane] = f2bf(v);
    if (lane == 0) rinv[g] = 1.0f / (sqrtf(ss) + 1e-8f);
}

// ---- init: zero T0, T1, accum ----
__global__ void init_k(float* T0, float* T1, float* accum){
    int i = blockIdx.x * 256 + threadIdx.x;   // 3*8192 = 24576
    T0[i] = 0.0f; T1[i] = 0.0f;
    if (i == 0) accum[0] = 0.0f;
}

// ---- MFMA Gibbs + fused first colsum ----
__global__ __launch_bounds__(256) void gibbs_mfma(
        const u16* __restrict__ xb, const float* __restrict__ rinv,
        u16* __restrict__ Kbase, float* __restrict__ T0){
    int zz = blockIdx.z;                 // 0..11
    int q = zz >> 2, b = zz & 3;
    int qa = (q == 1) ? 2 : 0;
    int qb = (q == 2) ? 2 : 1;
    const u16* Ab = xb + ((size_t)qa * BB + b) * NN * DD;
    const u16* Bb = xb + ((size_t)qb * BB + b) * NN * DD;
    const float* ainv = rinv + (size_t)qa * BB * NN + b * NN;
    const float* binv = rinv + (size_t)qb * BB * NN + b * NN;
    u16* K = Kbase + ((size_t)q * BB + b) * NM;
    float* tp = T0 + ((size_t)q * BB + b) * NN;

    int n0 = blockIdx.y * 128, m0 = blockIdx.x * 128;
    int tid = threadIdx.x;
    int wave = tid >> 6, lane = tid & 63;
    int wr = wave >> 1, wc = wave & 1;
    int l16 = lane & 15, lk = (lane >> 4) * 8;

    bf16x8 af[4][2], bfr[4][2];
    #pragma unroll
    for (int i = 0; i < 4; i++){
        #pragma unroll
        for (int ks = 0; ks < 2; ks++){
            af[i][ks]  = *reinterpret_cast<const bf16x8*>(
                Ab + (size_t)(n0 + wr * 64 + i * 16 + l16) * DD + ks * 32 + lk);
            bfr[i][ks] = *reinterpret_cast<const bf16x8*>(
                Bb + (size_t)(m0 + wc * 64 + i * 16 + l16) * DD + ks * 32 + lk);
        }
    }
    f32x4 acc[4][4] = {};
    #pragma unroll
    for (int ks = 0; ks < 2; ks++)
        #pragma unroll
        for (int i = 0; i < 4; i++)
            #pragma unroll
            for (int j = 0; j < 4; j++)
                acc[i][j] = __builtin_amdgcn_mfma_f32_16x16x32_bf16(
                    af[i][ks], bfr[j][ks], acc[i][j], 0, 0, 0);

    int rbase = (lane >> 4) * 4;
    float bi[4];
    #pragma unroll
    for (int j = 0; j < 4; j++) bi[j] = binv[m0 + wc * 64 + j * 16 + l16];
    float csum[4] = {};
    #pragma unroll
    for (int i = 0; i < 4; i++){
        #pragma unroll
        for (int r = 0; r < 4; r++){
            int n = n0 + wr * 64 + i * 16 + rbase + r;
            float ai = ainv[n];
            u16* krow = K + (size_t)n * NN + m0 + wc * 64 + l16;
            #pragma unroll
            for (int j = 0; j < 4; j++){
                float cosv = acc[i][j][r] * ai * bi[j];
                float kv = __expf(fmaf(10.0f, cosv, -10.0f));
                krow[j * 16] = f2bf(kv);
                csum[j] += kv;
            }
        }
    }
    #pragma unroll
    for (int j = 0; j < 4; j++){
        csum[j] += __shfl_xor(csum[j], 16, 64);
        csum[j] += __shfl_xor(csum[j], 32, 64);
    }
    if (lane < 16){
        #pragma unroll
        for (int j = 0; j < 4; j++)
            atomicAdd(&tp[m0 + wc * 64 + j * 16 + l16], csum[j]);
    }
}

// ---- merged colsum ----
__global__ void csum_all(const u16* __restrict__ Kbase, const float* __restrict__ R,
                         float* __restrict__ T){
    int b = blockIdx.x, z = blockIdx.z;
    int r0 = blockIdx.y * 32;
    int c0 = threadIdx.x * 8;
    const u16* Kp = Kbase + (size_t)z * BB * NM + ((size_t)b * NN + r0) * NN + c0;
    const float* xb = R + ((size_t)z * BB + b) * NN + r0;
    float acc[8] = {};
    #pragma unroll 4
    for (int r = 0; r < 32; r++){
        short8 kv = *reinterpret_cast<const short8*>(Kp + (size_t)r * NN);
        float xv = xb[r];
        #pragma unroll
        for (int j = 0; j < 8; j++) acc[j] = fmaf(bf2f((u16)kv[j]), xv, acc[j]);
    }
    float* tp = T + ((size_t)z * BB + b) * NN + c0;
    #pragma unroll
    for (int j = 0; j < 8; j++) atomicAdd(&tp[j], acc[j]);
}

// ---- merged rowsum ----
__global__ void rsum_all(const u16* __restrict__ Kbase, const float* __restrict__ T,
                         float* __restrict__ Cv, float* __restrict__ R,
                         float* __restrict__ Tnext){
    __shared__ float ysh[NN];
    int b = blockIdx.x, rg = blockIdx.y, z = blockIdx.z;
    int tid = threadIdx.x;
    const float* tb = T + ((size_t)z * BB + b) * NN;
    for (int m = tid; m < NN; m += 256)
        ysh[m] = powfi(tb[m]);
    __syncthreads();
    if (rg == 0){
        float* cvp = Cv + ((size_t)z * BB + b) * NN;
        float* tzp = Tnext + ((size_t)z * BB + b) * NN;
        for (int m = tid; m < NN; m += 256){
            cvp[m] = ysh[m];
            tzp[m] = 0.0f;
        }
    }
    int wave = tid >> 6, lane = tid & 63;
    int rsub = lane >> 4, l16 = lane & 15;
    int g = wave * 4 + rsub;
    const u16* Kz = Kbase + (size_t)z * BB * NM + (size_t)b * NN * NN;
    float* Rp = R + ((size_t)z * BB + b) * NN;
    #pragma unroll
    for (int h = 0; h < 2; h++){
        int r = rg * 32 + h * 16 + g;
        const u16* Kp = Kz + (size_t)r * NN;
        float acc = 0.0f;
        #pragma unroll 4
        for (int c = 0; c < 16; c++){
            int m = c * 128 + l16 * 8;
            short8 kv = *reinterpret_cast<const short8*>(Kp + m);
            f32x4 y0 = *reinterpret_cast<const f32x4*>(&ysh[m]);
            f32x4 y1 = *reinterpret_cast<const f32x4*>(&ysh[m + 4]);
            acc = fmaf(bf2f((u16)kv[0]), y0.x, acc);
            acc = fmaf(bf2f((u16)kv[1]), y0.y, acc);
            acc = fmaf(bf2f((u16)kv[2]), y0.z, acc);
            acc = fmaf(bf2f((u16)kv[3]), y0.w, acc);
            acc = fmaf(bf2f((u16)kv[4]), y1.x, acc);
            acc = fmaf(bf2f((u16)kv[5]), y1.y, acc);
            acc = fmaf(bf2f((u16)kv[6]), y1.z, acc);
            acc = fmaf(bf2f((u16)kv[7]), y1.w, acc);
        }
        acc += __shfl_xor(acc, 1, 64);
        acc += __shfl_xor(acc, 2, 64);
        acc += __shfl_xor(acc, 4, 64);
        acc += __shfl_xor(acc, 8, 64);
        if (l16 == 0) Rp[r] = powfi(acc);
    }
}

// ---- in-place scale: K1[b,n,k] *= v1[b,k]*u2[b,k], bf16 ----
__global__ void scale_k(u16* __restrict__ K1, const float* __restrict__ v1,
                        const float* __restrict__ u2){
    size_t i = ((size_t)blockIdx.x * 256 + threadIdx.x) * 8;
    int k = (int)(i & (NN - 1));
    int b = (int)(i >> 22);
    short8 kv = *reinterpret_cast<const short8*>(K1 + i);
    const float* vv = v1 + b * NN + k;
    const float* uu = u2 + b * NN + k;
    #pragma unroll
    for (int j = 0; j < 8; j++){
        float w = vv[j] * uu[j];
        kv[j] = (short)f2bf(bf2f((u16)kv[j]) * w);
    }
    *reinterpret_cast<short8*>(K1 + i) = kv;
}

// ---- deep-pipelined 256x256 MFMA fused final GEMM + |diff| reduce ----
// 8 waves (2x4), BK=32, 4-deep LDS ring, T2 XOR swizzle, counted vmcnt(6), setprio.
__global__ __launch_bounds__(512) void fgemm_k(
        const u16* __restrict__ A, const u16* __restrict__ BT,
        const u16* __restrict__ K3,
        const float* __restrict__ u1, const float* __restrict__ v2,
        const float* __restrict__ u3, const float* __restrict__ v3,
        float* __restrict__ accum){
    __shared__ __align__(16) u16 lds[65536];   // 4 ring bufs x (A 8192 + B 8192) u16 = 128 KB
    __shared__ float red[8];
    int b  = blockIdx.z;
    int n0 = blockIdx.y * 256, m0 = blockIdx.x * 256;
    int tid = threadIdx.x;
    int w = tid >> 6, lane = tid & 63;
    int wr = w >> 2, wn = w & 3;               // 2 x 4 waves; per-wave C: 128 x 64
    const u16* Ag = A  + (size_t)b * NM;
    const u16* Bg = BT + (size_t)b * NM;

    // staging geometry: wave w stages 16-row blocks {2w, 2w+1} of A and of B.
    // Pre-swizzled source chunk (rule 21: linear LDS dest + inverse-swz source).
    int srow   = lane >> 2;                        // row within 16-row block
    int schunk = (lane & 3) ^ ((lane >> 3) & 3);   // chunk ^ f(row), f=(row>>1)&3
    const u16* aSrc = Ag + (size_t)(n0 + w * 32 + srow) * NN + schunk * 8;
    const u16* bSrc = Bg + (size_t)(m0 + w * 32 + srow) * NN + schunk * 8;
    int dA = w * 1024;                             // u16 offset of wave's A dest
    int dB = 8192 + w * 1024;

    // read-side swizzled offsets
    int l16 = lane & 15;
    int fl  = (l16 >> 1) & 3;
    int kch = (lane >> 4) ^ fl;
    int aoff = (wr * 128 + l16) * 32 + kch * 8;    // + mf*512
    int boff = 8192 + (wn * 64 + l16) * 32 + kch * 8;  // + nf*512

    f32x4 acc[8][4] = {};

    // prologue: stage ring tiles 0,1,2
    #pragma unroll
    for (int kt = 0; kt < 3; kt++){
        const u16* as = aSrc + kt * 32;
        const u16* bs = bSrc + kt * 32;
        u16* da = lds + kt * 16384 + dA;
        u16* db = lds + kt * 16384 + dB;
        GLOAD16(as, da);           GLOAD16(as + 16 * NN, da + 512);
        GLOAD16(bs, db);           GLOAD16(bs + 16 * NN, db + 512);
    }
    asm volatile("s_waitcnt vmcnt(0)" ::: "memory");
    __builtin_amdgcn_s_barrier();

    for (int kt = 0; kt < 64; kt++){
        const u16* tb = lds + (size_t)(kt & 3) * 16384;
        // ---------- phase 0: nf 0,1 ----------
        bf16x8 af[8], bf0[2];
        #pragma unroll
        for (int mf = 0; mf < 8; mf++)
            af[mf] = *reinterpret_cast<const bf16x8*>(tb + aoff + mf * 512);
        bf0[0] = *reinterpret_cast<const bf16x8*>(tb + boff);
        bf0[1] = *reinterpret_cast<const bf16x8*>(tb + boff + 512);
        if (kt < 61){
            const u16* as = aSrc + (kt + 3) * 32;
            u16* da = lds + (size_t)((kt + 3) & 3) * 16384 + dA;
            GLOAD16(as, da);       GLOAD16(as + 16 * NN, da + 512);
        }
        asm volatile("s_waitcnt vmcnt(6)" ::: "memory");
        __builtin_amdgcn_s_barrier();
        asm volatile("s_waitcnt lgkmcnt(0)" ::: "memory");
        __builtin_amdgcn_sched_barrier(0);
        __builtin_amdgcn_s_setprio(1);
        #pragma unroll
        for (int mf = 0; mf < 8; mf++){
            acc[mf][0] = __builtin_amdgcn_mfma_f32_16x16x32_bf16(af[mf], bf0[0], acc[mf][0], 0, 0, 0);
            acc[mf][1] = __builtin_amdgcn_mfma_f32_16x16x32_bf16(af[mf], bf0[1], acc[mf][1], 0, 0, 0);
        }
        __builtin_amdgcn_s_setprio(0);
        __builtin_amdgcn_s_barrier();
        // ---------- phase 1: nf 2,3 ----------
        bf16x8 bf1[2];
        bf1[0] = *reinterpret_cast<const bf16x8*>(tb + boff + 1024);
        bf1[1] = *reinterpret_cast<const bf16x8*>(tb + boff + 1536);
        if (kt < 61){
            const u16* bs = bSrc + (kt + 3) * 32;
            u16* db = lds + (size_t)((kt + 3) & 3) * 16384 + dB;
            GLOAD16(bs, db);       GLOAD16(bs + 16 * NN, db + 512);
        }
        asm volatile("s_waitcnt vmcnt(6)" ::: "memory");
        __builtin_amdgcn_s_barrier();
        asm volatile("s_waitcnt lgkmcnt(0)" ::: "memory");
        __builtin_amdgcn_sched_barrier(0);
        __builtin_amdgcn_s_setprio(1);
        #pragma unroll
        for (int mf = 0; mf < 8; mf++){
            acc[mf][2] = __builtin_amdgcn_mfma_f32_16x16x32_bf16(af[mf], bf1[0], acc[mf][2], 0, 0, 0);
            acc[mf][3] = __builtin_amdgcn_mfma_f32_16x16x32_bf16(af[mf], bf1[1], acc[mf][3], 0, 0, 0);
        }
        __builtin_amdgcn_s_setprio(0);
        __builtin_amdgcn_s_barrier();
    }

    // epilogue: |u3*K3*v3 - u1*C*v2|
    const u16* K3b = K3 + (size_t)b * NM;
    int rb4 = (lane >> 4) * 4;
    float part = 0.0f;
    #pragma unroll
    for (int mf = 0; mf < 8; mf++){
        #pragma unroll
        for (int r = 0; r < 4; r++){
            int n = n0 + wr * 128 + mf * 16 + rb4 + r;
            float u1n = u1[b * NN + n], u3n = u3[b * NN + n];
            const u16* k3row = K3b + (size_t)n * NN + m0 + wn * 64 + l16;
            #pragma unroll
            for (int nf = 0; nf < 4; nf++){
                int m = m0 + wn * 64 + nf * 16 + l16;
                float find = u1n * acc[mf][nf][r] * v2[b * NN + m];
                float fdir = u3n * bf2f(k3row[nf * 16]) * v3[b * NN + m];
                part += fabsf(fdir - find);
            }
        }
    }
    #pragma unroll
    for (int o = 32; o >= 1; o >>= 1) part += __shfl_xor(part, o, 64);
    if (lane == 0) red[w] = part;
    __syncthreads();
    if (tid == 0){
        float s = 0.0f;
        #pragma unroll
        for (int i = 0; i < 8; i++) s += red[i];
        atomicAdd(accum, s);
    }
}

__global__ void fin_k(const float* __restrict__ accum, float* __restrict__ out){
    out[0] = accum[0] * (1.0f / 16777216.0f);
}

extern "C" void kernel_launch(void* const* d_in, const int* in_sizes, int n_in,
                              void* d_out, int out_size, void* d_ws, size_t ws_size,
                              hipStream_t stream){
    const float* fs = (const float*)d_in[0];
    const float* ft = (const float*)d_in[1];
    const float* fg = (const float*)d_in[2];
    float* out = (float*)d_out;
    char* ws = (char*)d_ws;

    size_t o = 0;
    u16* Kbase = (u16*)(ws + o); o += (size_t)3 * BB * NM * sizeof(u16);  // K1,K2T,K3
    u16* xb    = (u16*)(ws + o); o += (size_t)3 * BB * NN * DD * sizeof(u16);
    float* rinv = (float*)(ws + o); o += (size_t)3 * BB * NN * sizeof(float);
    float* R  = (float*)(ws + o); o += (size_t)3 * BB * NN * sizeof(float); // u1,v2,u3
    float* Cv = (float*)(ws + o); o += (size_t)3 * BB * NN * sizeof(float); // v1,u2,v3
    float* T0 = (float*)(ws + o); o += (size_t)3 * BB * NN * sizeof(float);
    float* T1 = (float*)(ws + o); o += (size_t)3 * BB * NN * sizeof(float);
    float* accum = (float*)(ws + o); o += 256;

    u16* K1  = Kbase;
    u16* K2T = Kbase + (size_t)BB * NM;
    u16* K3  = Kbase + (size_t)2 * BB * NM;

    // 1) zero T0/T1/accum (T0 receives gibbs colsum atomics)
    init_k<<<96, 256, 0, stream>>>(T0, T1, accum);

    // 2) bf16 features + inverse norms
    norm_prep<<<6144, 256, 0, stream>>>(fs, ft, fg, xb, rinv);

    // 3) MFMA Gibbs, first colsum fused (T0 = K^T 1 per z)
    gibbs_mfma<<<dim3(16, 16, 12), 256, 0, stream>>>(xb, rinv, Kbase, T0);

    // 4) Sinkhorn remainder: rsum, csum, rsum  (== 2 full damped iterations)
    rsum_all<<<dim3(BB, 64, 3), 256, 0, stream>>>(Kbase, T0, Cv, R, T1);
    csum_all<<<dim3(BB, 64, 3), 256, 0, stream>>>(Kbase, R, T1);
    rsum_all<<<dim3(BB, 64, 3), 256, 0, stream>>>(Kbase, T1, Cv, R, T0);
    // R = {u1, v2, u3}, Cv = {v1, u2, v3}

    // 5) K1 <- K1 * diag(v1*u2)
    scale_k<<<8192, 256, 0, stream>>>(K1, Cv, Cv + (size_t)BB * NN);

    // 6) deep-pipelined fused MFMA GEMM + |diff|
    fgemm_k<<<dim3(8, 8, BB), 512, 0, stream>>>(K1, K2T, K3,
                                                R, R + (size_t)BB * NN,
                                                R + (size_t)2 * BB * NN,
                                                Cv + (size_t)2 * BB * NN, accum);

    // 7) finalize
    fin_k<<<1, 1, 0, stream>>>(accum, out);
}